// Round 10
// baseline (5985.599 us; speedup 1.0000x reference)
//
#include <hip/hip_runtime.h>
#include <math.h>

// ---------------------------------------------------------------------------
// Pointer-network decoder, 50 sequential greedy-decode steps.
// R13 = R12 (4905 us) + ONE change: LSTM gates fused into the la GEMM.
//   - gate-interleaved weights Wcih/Wchh (row 4j+g = unit j, gate g) so a
//     128-col tile holds 32 complete units; combined bias bc.
//   - two-phase K-loop (x@Wcih then h@Wchh, same acc) -> NO xh concat,
//     x_bf/xa_bf/h buffers keep their R12 roles.
//   - 64x128 tiles, grid (16,8,2)=256 blocks (all CUs busy).
//   - h ping-pong (hA/hB) since blocks write unit-slices others read.
//   gates_kernel + g_ws roundtrip (33 MB/step) deleted. 4 dispatches/step.
// ---------------------------------------------------------------------------

#define S_LEN 50
#define BATCH 512
#define HDIM  512
#define H4    2048
#define BH    (BATCH*HDIM)          // 262144
#define BS    (BATCH*S_LEN)         // 25600
#define KSPQ  4                     // split-K for the qg GEMM
#define MASK50 0x0003FFFFFFFFFFFFULL

typedef unsigned short u16;
typedef __attribute__((ext_vector_type(8))) short bf16x8;
typedef __attribute__((ext_vector_type(4))) float f32x4;

__device__ __forceinline__ float wave_sum(float v){
  #pragma unroll
  for (int o=32;o;o>>=1) v += __shfl_xor(v,o);
  return v;
}
__device__ __forceinline__ float wave_max(float v){
  #pragma unroll
  for (int o=32;o;o>>=1) v = fmaxf(v,__shfl_xor(v,o));
  return v;
}
// fast tanh: 1 - 2/(e^{2x}+1). v_exp_f32 + v_rcp_f32; saturates exactly.
__device__ __forceinline__ float tanh_fast(float x){
  float t = __expf(2.0f*x);
  return 1.0f - 2.0f*__builtin_amdgcn_rcpf(t + 1.0f);
}
__device__ __forceinline__ float sigmoid_fast(float x){
  return __builtin_amdgcn_rcpf(1.0f + __expf(-x));
}
__device__ __forceinline__ u16 f2b(float f){
  unsigned u = __float_as_uint(f);
  unsigned r = (u + 0x7fffu + ((u>>16)&1u)) >> 16;
  return (u16)r;
}
__device__ __forceinline__ float b2f(u16 h){ return __uint_as_float(((unsigned)h)<<16); }

// ---------------------------------------------------------------------------
// bf16 MFMA GEMM (prologue pa/fa + per-step qg). 128x128 tile, BK=64.
// ---------------------------------------------------------------------------
struct MArgs {
  const u16* A[4]; const u16* W[4]; const float* bias[4]; void* C[4];
  int M, N, K, lda, ksplit, out_bf16;
};

__global__ __launch_bounds__(256, 2) void mfma_gemm(MArgs g) {
  const int z = blockIdx.z;
  const u16* __restrict__ A = g.A[z];
  const u16* __restrict__ W = g.W[z];
  const float* __restrict__ bias = g.bias[z];
  const int N = g.N, K = g.K, lda = g.lda;
  const int mtile = blockIdx.y / g.ksplit;
  const int ksp   = blockIdx.y % g.ksplit;
  const int m0 = mtile*128, n0 = blockIdx.x*128;
  const int kc = K / g.ksplit;
  const int kbeg = ksp*kc, kend = kbeg+kc;

  __shared__ __align__(16) u16 sh[2*128*88];   // 45056 B
  u16* As = sh;
  u16* Bs = sh + 128*88;

  const int tid = threadIdx.x;
  const int wave = tid>>6, lane = tid&63;
  const int wm = (wave>>1)*64, wn = (wave&1)*64;
  const int m16 = lane&15, quad = lane>>4;

  f32x4 acc[4][4];
  #pragma unroll
  for (int i=0;i<4;i++)
    #pragma unroll
    for (int j=0;j<4;j++) acc[i][j] = (f32x4){0.f,0.f,0.f,0.f};

  for (int kt = kbeg; kt < kend; kt += 64) {
    uint4 av[4], wv[4];
    #pragma unroll
    for (int it=0; it<4; it++){
      int idx = tid + it*256;
      int r = idx>>3, c = idx&7;
      av[it] = *(const uint4*)(A + (size_t)(m0+r)*lda + kt + c*8);
      wv[it] = *(const uint4*)(W + (size_t)(n0+r)*K + kt + c*8);
    }
    __syncthreads();
    #pragma unroll
    for (int it=0; it<4; it++){
      int idx = tid + it*256;
      int r = idx>>3, c = idx&7;
      *(uint4*)&As[r*88 + c*8] = av[it];
      *(uint4*)&Bs[r*88 + c*8] = wv[it];
    }
    __syncthreads();
    #pragma unroll
    for (int ks=0; ks<2; ks++){
      bf16x8 af[4], bfr[4];
      #pragma unroll
      for (int i=0;i<4;i++) af[i] = *(const bf16x8*)&As[(wm + i*16 + m16)*88 + ks*32 + quad*8];
      #pragma unroll
      for (int j=0;j<4;j++) bfr[j] = *(const bf16x8*)&Bs[(wn + j*16 + m16)*88 + ks*32 + quad*8];
      #pragma unroll
      for (int i=0;i<4;i++)
        #pragma unroll
        for (int j=0;j<4;j++)
          acc[i][j] = __builtin_amdgcn_mfma_f32_16x16x32_bf16(af[i], bfr[j], acc[i][j], 0, 0, 0);
    }
  }

  if (g.out_bf16) {
    u16* C = (u16*)g.C[z];
    __syncthreads();
    #pragma unroll
    for (int i=0;i<4;i++){
      #pragma unroll
      for (int j=0;j<4;j++){
        int cc = wn + j*16 + m16;
        float bv = bias ? bias[n0 + cc] : 0.0f;
        #pragma unroll
        for (int r=0;r<4;r++)
          sh[(wm + i*16 + quad*4 + r)*128 + cc] = f2b(acc[i][j][r] + bv);
      }
    }
    __syncthreads();
    #pragma unroll
    for (int k=0;k<8;k++){
      int idx = tid + k*256;
      int row = idx>>4, c = idx&15;
      *(uint4*)(C + (size_t)(m0+row)*N + n0 + c*8) = *(const uint4*)&sh[row*128 + c*8];
    }
  } else {
    float* C = (float*)g.C[z] + (size_t)ksp*g.M*N;
    float* shf = (float*)sh;
    __syncthreads();
    if (wm == 0){
      #pragma unroll
      for (int i=0;i<4;i++){
        int mb = i*16 + quad*4;
        #pragma unroll
        for (int j=0;j<4;j++){
          int cc = wn + j*16 + m16;
          float bv = bias ? bias[n0 + cc] : 0.0f;
          #pragma unroll
          for (int r=0;r<4;r++) shf[(mb+r)*128 + cc] = acc[i][j][r] + bv;
        }
      }
    }
    __syncthreads();
    #pragma unroll
    for (int k=0;k<8;k++){
      int idx = tid + k*256;
      int row = idx>>5, c = idx&31;
      *(float4*)(C + (size_t)(m0 + row)*N + n0 + c*4) = *(const float4*)&shf[row*128 + c*4];
    }
    __syncthreads();
    if (wm == 64){
      #pragma unroll
      for (int i=0;i<4;i++){
        int mb = i*16 + quad*4;
        #pragma unroll
        for (int j=0;j<4;j++){
          int cc = wn + j*16 + m16;
          float bv = bias ? bias[n0 + cc] : 0.0f;
          #pragma unroll
          for (int r=0;r<4;r++) shf[(mb+r)*128 + cc] = acc[i][j][r] + bv;
        }
      }
    }
    __syncthreads();
    #pragma unroll
    for (int k=0;k<8;k++){
      int idx = tid + k*256;
      int row = idx>>5, c = idx&31;
      *(float4*)(C + (size_t)(m0 + 64 + row)*N + n0 + c*4) = *(const float4*)&shf[row*128 + c*4];
    }
  }
}

// ---------------------------------------------------------------------------
// Fused LSTM: g = x@Wcih^T + h@Wchh^T + bc (gate-interleaved), nonlinearity
// in-epilogue. 64x128 tile, grid (16,8,2) = 256 blocks, 4 waves (2x2 of
// 32x64). Two-phase K-loop over separate x/h buffers. Writes h (ping-pong)
// bf16 + c fp32 in place (unique per-block ownership of (rows, units)).
// ---------------------------------------------------------------------------
__global__ __launch_bounds__(256, 2) void lstm_fused(
    const u16* __restrict__ x_bf, const u16* __restrict__ xa_bf,
    const u16* __restrict__ h_cur, u16* __restrict__ h_nxt,
    const u16* __restrict__ Wcih, const u16* __restrict__ Wchh,
    const float* __restrict__ bc, float* __restrict__ c_ws){
  const int z = blockIdx.z;
  const u16* Ax = z ? xa_bf : x_bf;
  const u16* Ah = h_cur + (size_t)z*BH;
  const u16* Wi = Wcih + (size_t)z*H4*HDIM;
  const u16* Wh = Wchh + (size_t)z*H4*HDIM;
  const float* bias = bc + (size_t)z*H4;
  float* Cst = c_ws + (size_t)z*BH;
  u16* Hd = h_nxt + (size_t)z*BH;
  const int m0 = blockIdx.y*64, n0 = blockIdx.x*128;

  __shared__ __align__(16) char smem[32768];   // As(9216)+Bs(18432) | epi(32768)
  u16* As = (u16*)smem;                        // [64][72]
  u16* Bs = (u16*)(smem + 9216);               // [128][72]

  const int tid = threadIdx.x;
  const int wave = tid>>6, lane = tid&63;
  const int wm = (wave>>1)*32, wn = (wave&1)*64;
  const int m16 = lane&15, quad = lane>>4;

  f32x4 acc[2][4];
  #pragma unroll
  for (int i=0;i<2;i++)
    #pragma unroll
    for (int j=0;j<4;j++) acc[i][j] = (f32x4){0.f,0.f,0.f,0.f};

  for (int kt = 0; kt < 1024; kt += 64) {
    const u16* A = (kt < 512) ? Ax : Ah;
    const u16* W = (kt < 512) ? Wi : Wh;
    const int kc = kt & 511;
    uint4 av[2], wv[4];
    #pragma unroll
    for (int it=0; it<2; it++){
      int idx = tid + it*256;
      int r = idx>>3, c = idx&7;
      av[it] = *(const uint4*)(A + (size_t)(m0+r)*HDIM + kc + c*8);
    }
    #pragma unroll
    for (int it=0; it<4; it++){
      int idx = tid + it*256;
      int r = idx>>3, c = idx&7;
      wv[it] = *(const uint4*)(W + (size_t)(n0+r)*HDIM + kc + c*8);
    }
    __syncthreads();
    #pragma unroll
    for (int it=0; it<2; it++){
      int idx = tid + it*256; int r = idx>>3, c = idx&7;
      *(uint4*)&As[r*72 + c*8] = av[it];
    }
    #pragma unroll
    for (int it=0; it<4; it++){
      int idx = tid + it*256; int r = idx>>3, c = idx&7;
      *(uint4*)&Bs[r*72 + c*8] = wv[it];
    }
    __syncthreads();
    #pragma unroll
    for (int ks=0; ks<2; ks++){
      bf16x8 af[2], bfr[4];
      #pragma unroll
      for (int i=0;i<2;i++) af[i] = *(const bf16x8*)&As[(wm + i*16 + m16)*72 + ks*32 + quad*8];
      #pragma unroll
      for (int j=0;j<4;j++) bfr[j] = *(const bf16x8*)&Bs[(wn + j*16 + m16)*72 + ks*32 + quad*8];
      #pragma unroll
      for (int i=0;i<2;i++)
        #pragma unroll
        for (int j=0;j<4;j++)
          acc[i][j] = __builtin_amdgcn_mfma_f32_16x16x32_bf16(af[i], bfr[j], acc[i][j], 0, 0, 0);
    }
  }

  // stage fp32 gate tile [64][128] through LDS, then LSTM nonlinearity
  __syncthreads();
  float* epi = (float*)smem;
  #pragma unroll
  for (int i=0;i<2;i++){
    int mb = wm + i*16 + quad*4;
    #pragma unroll
    for (int j=0;j<4;j++){
      int cb = wn + j*16 + m16;
      #pragma unroll
      for (int r=0;r<4;r++) epi[(mb+r)*128 + cb] = acc[i][j][r];
    }
  }
  __syncthreads();
  #pragma unroll
  for (int k=0;k<8;k++){
    int p = tid + k*256;                       // 64 rows x 32 units
    int u = p & 31, row = p >> 5;
    float4 gv = *(const float4*)&epi[row*128 + u*4];
    int bcol = n0 + u*4;
    float gi = gv.x + bias[bcol+0];
    float gf = gv.y + bias[bcol+1];
    float gg = gv.z + bias[bcol+2];
    float go = gv.w + bias[bcol+3];
    int brow = m0 + row;
    int jj = (n0>>2) + u;
    size_t ci = (size_t)brow*HDIM + jj;
    float cp = Cst[ci];
    float c2 = sigmoid_fast(gf)*cp + sigmoid_fast(gi)*tanh_fast(gg);
    float h2 = sigmoid_fast(go)*tanh_fast(c2);
    Cst[ci] = c2;
    Hd[(size_t)brow*HDIM + jj] = f2b(h2);
  }
}

// ---------------------------------------------------------------------------
// Batched fp32 -> bf16 conversions (job per blockIdx.y)
// ---------------------------------------------------------------------------
struct F2BJobs { const float* s[8]; u16* d[8]; int n4; };

__global__ void f2b_multi(F2BJobs J){
  const float* __restrict__ src = J.s[blockIdx.y];
  u16* __restrict__ dst = J.d[blockIdx.y];
  int i = blockIdx.x*blockDim.x + threadIdx.x;
  if (i >= J.n4) return;
  float4 v = *(const float4*)(src + (size_t)i*4);
  ushort4 o; o.x=f2b(v.x); o.y=f2b(v.y); o.z=f2b(v.z); o.w=f2b(v.w);
  *(ushort4*)(dst + (size_t)i*4) = o;
}

// Gate-interleaved weight conversion: dst row 4j+g = src row g*512+j (bf16)
struct WPJobs { const float* s[4]; u16* d[4]; };
__global__ void wperm_multi(WPJobs J){
  const float* __restrict__ src = J.s[blockIdx.y];
  u16* __restrict__ dst = J.d[blockIdx.y];
  int i = blockIdx.x*blockDim.x + threadIdx.x;     // over 2048*512/4
  if (i >= H4*HDIM/4) return;
  int elem = i*4;
  int r = elem >> 9;
  int c = elem & 511;
  int srcrow = (r&3)*512 + (r>>2);
  float4 v = *(const float4*)(src + (size_t)srcrow*HDIM + c);
  ushort4 o; o.x=f2b(v.x); o.y=f2b(v.y); o.z=f2b(v.z); o.w=f2b(v.w);
  *(ushort4*)(dst + elem) = o;
}

// Combined gate-interleaved bias: bc[z][4j+g] = b_ih[g*512+j] + b_hh[g*512+j]
__global__ void bcomb_kernel(const float* __restrict__ bih, const float* __restrict__ bhh,
                             const float* __restrict__ biha, const float* __restrict__ bhha,
                             float* __restrict__ bc){
  int i = blockIdx.x*blockDim.x + threadIdx.x;
  if (i >= 2*H4) return;
  int z = i >> 11, r = i & 2047;
  int srcrow = (r&3)*512 + (r>>2);
  bc[i] = (z ? biha : bih)[srcrow] + (z ? bhha : bhh)[srcrow];
}

// [S,B,H] fp32 -> [(b*S+s),H] bf16; blockIdx.y picks job
__global__ void remap2_kernel(const float* __restrict__ srcA, u16* __restrict__ dstA,
                              const float* __restrict__ srcB, u16* __restrict__ dstB){
  const float* __restrict__ src = blockIdx.y ? srcB : srcA;
  u16* __restrict__ dst = blockIdx.y ? dstB : dstA;
  int i = blockIdx.x*blockDim.x + threadIdx.x;
  if (i >= (S_LEN*BATCH*HDIM)/4) return;
  int elem = i*4;
  int s = elem >> 18;
  int b = (elem >> 9) & 511;
  int h = elem & 511;
  float4 v = *(const float4*)(src + (size_t)s*BATCH*HDIM + (size_t)b*HDIM + h);
  ushort4 o; o.x=f2b(v.x); o.y=f2b(v.y); o.z=f2b(v.z); o.w=f2b(v.w);
  *(ushort4*)(dst + ((size_t)b*S_LEN + s)*HDIM + h) = o;
}

// ---------------------------------------------------------------------------
// init: states + decoder inputs (bf16 activations, fp32 c), mask
// ---------------------------------------------------------------------------
__global__ void init_kernel(const float* __restrict__ h0, const float* __restrict__ c0,
                            const float* __restrict__ h0a, const float* __restrict__ c0a,
                            const float* __restrict__ dec, const unsigned char* __restrict__ vmask,
                            u16* __restrict__ hA, float* __restrict__ c_ws,
                            u16* __restrict__ x_bf, u16* __restrict__ xa_bf,
                            int* __restrict__ mask){
  for (int i = blockIdx.x*blockDim.x + threadIdx.x; i < BH; i += gridDim.x*blockDim.x) {
    hA[i]=f2b(h0[i]); hA[BH+i]=f2b(h0a[i]);
    c_ws[i]=c0[i];    c_ws[BH+i]=c0a[i];
    u16 d = f2b(dec[i]);
    x_bf[i]=d; xa_bf[i]=d;
    if (i < BS) mask[i] = vmask[i] ? 1 : 0;
  }
}

__global__ __launch_bounds__(64) void mask_fix_kernel(int* __restrict__ mask){
  int b = blockIdx.x, lane = threadIdx.x;
  int mv = (lane < S_LEN) ? mask[b*S_LEN+lane] : 1;
  unsigned long long bal = __ballot(mv != 0);
  if ((bal & MASK50) == MASK50 && lane == 49) mask[b*S_LEN+49] = 0;
}

// ---------------------------------------------------------------------------
// Glimpse attention + pointer-q (F-trick): logits from e, softmax, then
// q2 = bq_p + sum_s p_s * F[b,s,:] directly.
// ---------------------------------------------------------------------------
__global__ __launch_bounds__(512) void glimpse_kernel(
    const float* __restrict__ qpart,
    const float* __restrict__ bq_g, const float* __restrict__ bq_ga,
    const u16* __restrict__ e_g, const u16* __restrict__ e_ga,
    const float* __restrict__ v_g, const float* __restrict__ v_ga,
    const u16* __restrict__ F_m, const u16* __restrict__ F_a,
    const float* __restrict__ bq_p, const float* __restrict__ bq_pa,
    const int* __restrict__ mask, float* __restrict__ q2_ws){
  int z = blockIdx.y, b = blockIdx.x, tid = threadIdx.x;
  const u16* e = (z ? e_ga : e_g) + (size_t)b*S_LEN*HDIM;
  const float* v  = z ? v_ga : v_g;
  const float* bq = z ? bq_ga : bq_g;
  const float* qp = qpart + (size_t)z*KSPQ*BH + (size_t)b*HDIM;
  __shared__ float lg_sh[64], p_sh[64];
  int w = tid>>6, lane = tid&63;
  int h0 = lane*8;
  float qreg[8], vreg[8];
  #pragma unroll
  for (int ii=0; ii<8; ii++){
    int h = h0+ii;
    float q = bq[h];
    #pragma unroll
    for (int p=0;p<KSPQ;p++) q += qp[(size_t)p*BH + h];
    qreg[ii]=q; vreg[ii]=v[h];
  }
  for (int s = w; s < S_LEN; s += 8) {
    uint4 ev = *(const uint4*)(e + (size_t)s*HDIM + h0);
    const u16* pe = (const u16*)&ev;
    float acc = 0.0f;
    #pragma unroll
    for (int ii=0; ii<8; ii++) acc += vreg[ii]*tanh_fast(qreg[ii] + b2f(pe[ii]));
    acc = wave_sum(acc);
    if (lane==0) lg_sh[s] = mask[b*S_LEN+s] ? -INFINITY : acc;
  }
  __syncthreads();
  if (tid < 64) {
    float val = (tid < S_LEN) ? lg_sh[tid] : -INFINITY;
    float mx = wave_max(val);
    float ex = (tid < S_LEN) ? expf(val - mx) : 0.0f;
    float sm = wave_sum(ex);
    if (tid < S_LEN) p_sh[tid] = ex / sm;
  }
  __syncthreads();
  const u16* F = (z ? F_a : F_m) + (size_t)b*S_LEN*HDIM;
  float acc = (z ? bq_pa : bq_p)[tid];
  for (int s=0;s<S_LEN;s++) acc += p_sh[s]*b2f(F[(size_t)s*HDIM + tid]);
  q2_ws[(size_t)z*BH + (size_t)b*HDIM + tid] = acc;
}

// ---------------------------------------------------------------------------
// Fused pointer + combine + gather.
// ---------------------------------------------------------------------------
__global__ __launch_bounds__(512) void pointer_combine_kernel(
    const float* __restrict__ q2_ws,
    const u16* __restrict__ e_p, const u16* __restrict__ e_pa,
    const float* __restrict__ v_p, const float* __restrict__ v_pa,
    int* __restrict__ mask,
    const u16* __restrict__ emb_bf, const u16* __restrict__ ench_bf,
    u16* __restrict__ x_bf, u16* __restrict__ xa_bf,
    float* __restrict__ out, int t){
  int b = blockIdx.x, tid = threadIdx.x;
  int w = tid>>6, lane = tid&63;
  int z = w>>2, wz = w&3;
  __shared__ float sh_lp[2][64];
  __shared__ int idx_sh;

  const u16* ep = (z ? e_pa : e_p) + (size_t)b*S_LEN*HDIM;
  const float* vp = z ? v_pa : v_p;
  int h0 = lane*8;
  float q2r[8], vpr[8];
  const float* q2g = q2_ws + (size_t)z*BH + (size_t)b*HDIM + h0;
  #pragma unroll
  for (int ii=0; ii<8; ii++){ q2r[ii]=q2g[ii]; vpr[ii]=vp[h0+ii]; }
  for (int s = wz; s < S_LEN; s += 4) {
    uint4 ev = *(const uint4*)(ep + (size_t)s*HDIM + h0);
    const u16* pe = (const u16*)&ev;
    float acc = 0.0f;
    #pragma unroll
    for (int ii=0; ii<8; ii++) acc += vpr[ii]*tanh_fast(q2r[ii] + b2f(pe[ii]));
    acc = wave_sum(acc);
    if (lane==0) sh_lp[z][s] = mask[b*S_LEN+s] ? -INFINITY : 10.0f*tanh_fast(acc);
  }
  __syncthreads();

  if (tid < 64) {
    float a  = (lane < S_LEN) ? sh_lp[0][lane] : -INFINITY;
    float ca = (lane < S_LEN) ? sh_lp[1][lane] : -INFINITY;
    float m1 = wave_max(a);
    float l1 = logf(wave_sum((lane < S_LEN) ? expf(a - m1) : 0.0f));
    float m2 = wave_max(ca);
    float l2 = logf(wave_sum((lane < S_LEN) ? expf(ca - m2) : 0.0f));
    float logp = (a - m1 - l1) + 0.1f * (ca - m2 - l2);
    if (lane < S_LEN) out[(size_t)b*(S_LEN*S_LEN) + t*S_LEN + lane] = fmaxf(logp, -1e30f);
    float vv = (lane < S_LEN) ? logp : -INFINITY;
    int bi = lane;
    #pragma unroll
    for (int o=32;o;o>>=1) {
      float ov = __shfl_xor(vv, o); int oi = __shfl_xor(bi, o);
      if (ov > vv || (ov == vv && oi < bi)) { vv = ov; bi = oi; }
    }
    int idx = bi;
    if (lane == 0) { out[(size_t)BATCH*S_LEN*S_LEN + b*S_LEN + t] = (float)idx; idx_sh = idx; }
    int mv = 1;
    if (lane < S_LEN) { mv = mask[b*S_LEN+lane]; if (lane==idx) mv = 1; mask[b*S_LEN+lane] = mv; }
    unsigned long long bal = __ballot(mv != 0);
    if ((bal & MASK50) == MASK50 && lane == 49) mask[b*S_LEN+49] = 0;
  }
  __syncthreads();

  int idx = idx_sh;
  x_bf[(size_t)b*HDIM + tid]  = emb_bf[((size_t)idx*BATCH + b)*HDIM + tid];
  xa_bf[(size_t)b*HDIM + tid] = ench_bf[((size_t)idx*BATCH + b)*HDIM + tid];
}

// ---------------------------------------------------------------------------
extern "C" void kernel_launch(void* const* d_in, const int* in_sizes, int n_in,
                              void* d_out, int out_size, void* d_ws, size_t ws_size,
                              hipStream_t stream) {
  (void)in_sizes; (void)n_in; (void)out_size; (void)ws_size;
  const float* dec    = (const float*)d_in[0];
  const float* emb    = (const float*)d_in[1];
  const float* h0     = (const float*)d_in[2];
  const float* c0     = (const float*)d_in[3];
  const float* ctx    = (const float*)d_in[4];
  const float* ench   = (const float*)d_in[5];
  const float* dia    = (const float*)d_in[6];
  const float* h0a    = (const float*)d_in[7];
  const float* c0a    = (const float*)d_in[8];
  const unsigned char* vmask = (const unsigned char*)d_in[9];
  const float* W_ih   = (const float*)d_in[10];
  const float* W_hh   = (const float*)d_in[11];
  const float* b_ih   = (const float*)d_in[12];
  const float* b_hh   = (const float*)d_in[13];
  const float* W_ih_a = (const float*)d_in[14];
  const float* W_hh_a = (const float*)d_in[15];
  const float* b_ih_a = (const float*)d_in[16];
  const float* b_hh_a = (const float*)d_in[17];
  const float* Wq_p  = (const float*)d_in[18];
  const float* bq_p  = (const float*)d_in[19];
  const float* Wr_p  = (const float*)d_in[20];
  const float* br_p  = (const float*)d_in[21];
  const float* v_p   = (const float*)d_in[22];
  const float* Wq_pa = (const float*)d_in[23];
  const float* bq_pa = (const float*)d_in[24];
  const float* Wr_pa = (const float*)d_in[25];
  const float* br_pa = (const float*)d_in[26];
  const float* v_pa  = (const float*)d_in[27];
  const float* Wq_g  = (const float*)d_in[28];
  const float* bq_g  = (const float*)d_in[29];
  const float* Wr_g  = (const float*)d_in[30];
  const float* br_g  = (const float*)d_in[31];
  const float* v_g   = (const float*)d_in[32];
  const float* Wq_ga = (const float*)d_in[33];
  const float* bq_ga = (const float*)d_in[34];
  const float* Wr_ga = (const float*)d_in[35];
  const float* br_ga = (const float*)d_in[36];
  const float* v_ga  = (const float*)d_in[37];

  char* base = (char*)d_ws;
  size_t off = 0;
  auto carve = [&](size_t bytes)->char*{ char* p = base + off; off += (bytes + 255) & ~(size_t)255; return p; };

  const size_t E_BYTES = (size_t)BS*HDIM*2;      // 26,214,400
  u16* e_g   = (u16*)carve(E_BYTES);
  u16* e_p   = (u16*)carve(E_BYTES);
  u16* e_ga  = (u16*)carve(E_BYTES);
  u16* e_pa  = (u16*)carve(E_BYTES);
  u16* F_m   = (u16*)carve(E_BYTES);             // e_g  @ Wq_p^T  (hoisted)
  u16* F_a   = (u16*)carve(E_BYTES);             // e_ga @ Wq_pa^T
  char* scratch = carve(2*E_BYTES);              // A_ctx/A_dia, later emb/ench bf16
  u16* A_ctx  = (u16*)scratch;
  u16* A_dia  = (u16*)(scratch + E_BYTES);
  u16* emb_bf  = A_ctx;                          // aliases (prologue-ordered)
  u16* ench_bf = A_dia;
  u16* Wcih    = (u16*)carve((size_t)2*H4*HDIM*2);   // gate-interleaved [2][2048][512]
  u16* Wchh    = (u16*)carve((size_t)2*H4*HDIM*2);
  float* bc    = (float*)carve((size_t)2*H4*4);
  u16* Wqg_bf  = (u16*)carve((size_t)BH*2);      // 512x512
  u16* Wqga_bf = (u16*)carve((size_t)BH*2);
  u16* Wqp_bf  = (u16*)carve((size_t)BH*2);
  u16* Wqpa_bf = (u16*)carve((size_t)BH*2);
  u16* Wrg_bf  = (u16*)carve((size_t)BH*2);
  u16* Wrp_bf  = (u16*)carve((size_t)BH*2);
  u16* Wrga_bf = (u16*)carve((size_t)BH*2);
  u16* Wrpa_bf = (u16*)carve((size_t)BH*2);
  u16* x_bf    = (u16*)carve((size_t)BH*2);
  u16* xa_bf   = (u16*)carve((size_t)BH*2);
  u16* hA      = (u16*)carve((size_t)2*BH*2);    // [2][B][H] ping
  u16* hB      = (u16*)carve((size_t)2*BH*2);    // pong
  float* c_ws  = (float*)carve((size_t)2*BH*4);
  float* q_ws  = (float*)carve((size_t)2*KSPQ*BH*4);
  float* q2_ws = (float*)carve((size_t)2*BH*4);
  int*   mask  = (int*)carve((size_t)BS*4);
  float* out   = (float*)d_out;

  init_kernel<<<1024, 256, 0, stream>>>(h0, c0, h0a, c0a, dec, vmask,
                                        hA, c_ws, x_bf, xa_bf, mask);
  mask_fix_kernel<<<BATCH, 64, 0, stream>>>(mask);

  // --- prologue conversions (batched) ---
  const int RB = ((S_LEN*BATCH*HDIM/4)+255)/256;
  remap2_kernel<<<dim3(RB,2), 256, 0, stream>>>(ctx, A_ctx, dia, A_dia);

  const int NWP = H4*HDIM/4, NWQ = BH/4;
  WPJobs jw{};   // gate-interleave the 4 LSTM weight matrices
  jw.s[0]=W_ih;   jw.d[0]=Wcih;
  jw.s[1]=W_hh;   jw.d[1]=Wchh;
  jw.s[2]=W_ih_a; jw.d[2]=Wcih + (size_t)H4*HDIM;
  jw.s[3]=W_hh_a; jw.d[3]=Wchh + (size_t)H4*HDIM;
  wperm_multi<<<dim3((NWP+255)/256,4), 256, 0, stream>>>(jw);
  bcomb_kernel<<<(2*H4+255)/256, 256, 0, stream>>>(b_ih, b_hh, b_ih_a, b_hh_a, bc);

  F2BJobs jq{};   // 8 attention weight matrices [512x512]
  jq.s[0]=Wq_g;  jq.d[0]=Wqg_bf;  jq.s[1]=Wq_ga; jq.d[1]=Wqga_bf;
  jq.s[2]=Wq_p;  jq.d[2]=Wqp_bf;  jq.s[3]=Wq_pa; jq.d[3]=Wqpa_bf;
  jq.s[4]=Wr_g;  jq.d[4]=Wrg_bf;  jq.s[5]=Wr_p;  jq.d[5]=Wrp_bf;
  jq.s[6]=Wr_ga; jq.d[6]=Wrga_bf; jq.s[7]=Wr_pa; jq.d[7]=Wrpa_bf;
  jq.n4 = NWQ;
  f2b_multi<<<dim3((NWQ+255)/256,8), 256, 0, stream>>>(jq);

  // Hoisted context projections -> e (bf16, [B,S,H] row = b*S+s)
  MArgs pa{};
  pa.A[0]=A_ctx; pa.A[1]=A_ctx; pa.A[2]=A_dia; pa.A[3]=A_dia;
  pa.W[0]=Wrg_bf; pa.W[1]=Wrp_bf; pa.W[2]=Wrga_bf; pa.W[3]=Wrpa_bf;
  pa.bias[0]=br_g; pa.bias[1]=br_p; pa.bias[2]=br_ga; pa.bias[3]=br_pa;
  pa.C[0]=e_g; pa.C[1]=e_p; pa.C[2]=e_ga; pa.C[3]=e_pa;
  pa.M=BS; pa.N=HDIM; pa.K=HDIM; pa.lda=HDIM; pa.ksplit=1; pa.out_bf16=1;
  mfma_gemm<<<dim3(4,200,4), 256, 0, stream>>>(pa);

  // F = e_g @ Wq_p^T (and aoi): pointer-q projection hoisted by linearity
  MArgs fa{};
  fa.A[0]=e_g; fa.A[1]=e_ga;
  fa.W[0]=Wqp_bf; fa.W[1]=Wqpa_bf;
  fa.bias[0]=fa.bias[1]=nullptr;
  fa.C[0]=F_m; fa.C[1]=F_a;
  fa.M=BS; fa.N=HDIM; fa.K=HDIM; fa.lda=HDIM; fa.ksplit=1; fa.out_bf16=1;
  mfma_gemm<<<dim3(4,200,2), 256, 0, stream>>>(fa);

  // emb/ench bf16 copies into the (now dead) A_ctx/A_dia space
  const int NE = S_LEN*BATCH*HDIM/4;
  F2BJobs je{};
  je.s[0]=emb; je.d[0]=emb_bf; je.s[1]=ench; je.d[1]=ench_bf;
  je.n4 = NE;
  f2b_multi<<<dim3((NE+255)/256,2), 256, 0, stream>>>(je);

  // --- per-step qg GEMM arg sets (A = the h written by THIS step's lstm) ---
  MArgs qgE{};   // even t: nxt = hB
  qgE.A[0]=hB; qgE.A[1]=hB+BH;
  qgE.W[0]=Wqg_bf; qgE.W[1]=Wqga_bf;
  qgE.bias[0]=qgE.bias[1]=qgE.bias[2]=qgE.bias[3]=nullptr;
  qgE.C[0]=q_ws; qgE.C[1]=q_ws+(size_t)KSPQ*BH;
  qgE.M=BATCH; qgE.N=HDIM; qgE.K=HDIM; qgE.lda=HDIM; qgE.ksplit=KSPQ; qgE.out_bf16=0;
  MArgs qgO = qgE;   // odd t: nxt = hA
  qgO.A[0]=hA; qgO.A[1]=hA+BH;

  for (int t = 0; t < S_LEN; ++t) {
    u16* cur = (t&1) ? hB : hA;
    u16* nxt = (t&1) ? hA : hB;
    lstm_fused<<<dim3(16,8,2), 256, 0, stream>>>(x_bf, xa_bf, cur, nxt,
                                                 Wcih, Wchh, bc, c_ws);
    mfma_gemm<<<dim3(4,4*KSPQ,2), 256, 0, stream>>>((t&1) ? qgO : qgE);
    glimpse_kernel<<<dim3(BATCH,2), 512, 0, stream>>>(
        q_ws, bq_g, bq_ga, e_g, e_ga, v_g, v_ga,
        F_m, F_a, bq_p, bq_pa, mask, q2_ws);
    pointer_combine_kernel<<<BATCH, 512, 0, stream>>>(
        q2_ws, e_p, e_pa, v_p, v_pa,
        mask, emb_bf, ench_bf, x_bf, xa_bf, out, t);
  }
}